// Round 1
// 350.779 us; speedup vs baseline: 1.0101x; 1.0101x over previous
//
#include <hip/hip_runtime.h>

#define NB 32
#define NT 2048
#define ND 512
#define NH 64
#define NS 3
#define NBLKS 2
#define ROWLEN (2*ND + 1)   // 1025 floats per output row

typedef __attribute__((ext_vector_type(8))) short bf16x8;   // 8 bf16 = 4 VGPR (guide §3)
typedef float f32x4 __attribute__((ext_vector_type(4)));

// bf16 packed-weight workspace layout (ushort elements)
#define W1_OFF 0
#define W2_OFF 24576
#define WF_OFF 49152
#define WS_ELEMS 52224      // = 104448 bytes

__device__ __forceinline__ unsigned int f2bf(float f) {      // RNE f32->bf16
    unsigned int u = __float_as_uint(f);
    return (u + 0x7FFFu + ((u >> 16) & 1u)) >> 16;
}
__device__ __forceinline__ unsigned int pack2(float a, float b) {
    return f2bf(a) | (f2bf(b) << 16);
}

// Unit relabeling: packed row s holds LOGICAL unit uperm(s).
// Chosen so MFMA D-slots (16t+4q+e) of lane (r,q) are exactly the units that
// lane needs for the next matvec's B-fragment ({8q..8q+7} u {32+8q..32+8q+7}).
// => hidden-state chains entirely in registers: no LDS, no barriers.
__device__ __forceinline__ int uperm(int s) {
    return (((s >> 2) & 3) << 3) + (((s >> 4) & 1) << 2) + (s & 3) + ((s >> 5) << 5);
}

// One-shot (per launch) f32 -> bf16 weight conversion into d_ws.
// W1,W2: [S][NBLK][64][64] flat, rows gathered through uperm.
// Wf: [S][2][64] -> padded [S][16][64] (rows>=2 zero), no permutation (outputs
// land on D rows 0,1 which are slots 0,1 = logical rows 0,1).
__global__ __launch_bounds__(256) void prepack(
    const float* __restrict__ W1, const float* __restrict__ W2,
    const float* __restrict__ Wf, unsigned short* __restrict__ ws)
{
    int idx = blockIdx.x * 256 + threadIdx.x;
    if (idx < 24576) {
        int mat = idx >> 12, s = (idx >> 6) & 63, k = idx & 63;
        ws[W1_OFF + idx] = (unsigned short)f2bf(W1[(mat << 12) + uperm(s) * 64 + k]);
    } else if (idx < 49152) {
        int o = idx - 24576;
        int mat = o >> 12, s = (o >> 6) & 63, k = o & 63;
        ws[W2_OFF + o] = (unsigned short)f2bf(W2[(mat << 12) + uperm(s) * 64 + k]);
    } else if (idx < WS_ELEMS) {
        int o = idx - 49152;                 // [3][16][64]
        int s = o >> 10, row = (o >> 6) & 15, m = o & 63;
        float v = (row < 2) ? Wf[s * 128 + row * 64 + m] : 0.0f;
        ws[WF_OFF + o] = (unsigned short)f2bf(v);
    }
}

// Block = 256 threads (4 waves) handles 64 rows.
//  - feature part: 64 rows x 1024 coalesced f32 stores (the HBM floor), issued first
//  - flow part: each wave runs 16 rows through the MADE flow with bf16 MFMA,
//    hidden state register-resident throughout (unit permutation trick above).
__global__ __launch_bounds__(256, 4) void nf_main(
    const float* __restrict__ trend, const float* __restrict__ seasonal,
    const float* __restrict__ residual,
    const float* __restrict__ Wt, const float* __restrict__ bt,
    const float* __restrict__ Ws, const float* __restrict__ bs,
    const float* __restrict__ b_init, const float* __restrict__ Wc0,
    const float* __restrict__ bc0,
    const float* __restrict__ b1, const float* __restrict__ b2,
    const float* __restrict__ Wcb, const float* __restrict__ bcb,
    const float* __restrict__ bf_, const unsigned short* __restrict__ wpk,
    float* __restrict__ out)
{
    __shared__ float s_tr[64], s_se[64];

    const int tid  = threadIdx.x;
    const int row0 = blockIdx.x * 64;

    if (tid < 64) { s_tr[tid] = trend[row0 + tid]; s_se[tid] = seasonal[row0 + tid]; }
    __syncthreads();

    // ---------- feature part: fire-and-forget stores ----------
    {
        float wv[4], bv[4];
        #pragma unroll
        for (int j = 0; j < 4; ++j) {
            int cc = tid + 256 * j;
            if (cc < ND) { wv[j] = Wt[cc];      bv[j] = bt[cc]; }
            else         { wv[j] = Ws[cc - ND]; bv[j] = bs[cc - ND]; }
        }
        for (int rr = 0; rr < 64; ++rr) {
            float a = s_tr[rr], sv = s_se[rr];
            float* rp = out + (size_t)(row0 + rr) * ROWLEN;
            #pragma unroll
            for (int j = 0; j < 4; ++j) {
                int cc = tid + 256 * j;
                rp[cc] = fmaf((cc < ND) ? a : sv, wv[j], bv[j]);
            }
        }
    }

    // ---------- flow part (register-resident, no LDS, no barriers) ----------
    const int lane = tid & 63;
    const int wv_  = tid >> 6;
    const int r    = lane & 15;      // sample within wave tile; A-frag row, D col
    const int q    = lane >> 4;      // k-quad
    const int n    = row0 + wv_ * 16 + r;
    const float x  = residual[n];
    const float c  = ((n & (NT - 1)) == 0) ? 0.0f : residual[n - 1];

    // logical-unit base for D slot (16t+4q+e): unit = pbt[t] + e
    const int pb0 = 8 * q;
    const int pbt[4] = {pb0, pb0 + 4, pb0 + 32, pb0 + 36};

    union B8 { unsigned int u[4]; bf16x8 v; };

    float z = x, logdet = 0.0f;

    for (int i = 0; i < NS; ++i) {
        float h[4][4];
        #pragma unroll
        for (int t = 0; t < 4; ++t) {
            const int ub = i * NH + pbt[t];
            const f32x4 wc  = *(const f32x4*)(Wc0 + ub);
            const f32x4 b0v = *(const f32x4*)(bc0 + ub);
            const f32x4 biv = *(const f32x4*)(b_init + ub);
            #pragma unroll
            for (int e = 0; e < 4; ++e) h[t][e] = fmaf(c, wc[e], b0v[e] + biv[e]);
        }

        #pragma unroll
        for (int j = 0; j < NBLKS; ++j) {
            const int ij = i * NBLKS + j;

            // B-fragments = relu(h), assembled lane-locally:
            // bA regs e'=0..7 <-> units 8q+e', bB <-> units 32+8q+e'
            B8 bA, bB;
            bA.u[0] = pack2(fmaxf(h[0][0], 0.f), fmaxf(h[0][1], 0.f));
            bA.u[1] = pack2(fmaxf(h[0][2], 0.f), fmaxf(h[0][3], 0.f));
            bA.u[2] = pack2(fmaxf(h[1][0], 0.f), fmaxf(h[1][1], 0.f));
            bA.u[3] = pack2(fmaxf(h[1][2], 0.f), fmaxf(h[1][3], 0.f));
            bB.u[0] = pack2(fmaxf(h[2][0], 0.f), fmaxf(h[2][1], 0.f));
            bB.u[1] = pack2(fmaxf(h[2][2], 0.f), fmaxf(h[2][3], 0.f));
            bB.u[2] = pack2(fmaxf(h[3][0], 0.f), fmaxf(h[3][1], 0.f));
            bB.u[3] = pack2(fmaxf(h[3][2], 0.f), fmaxf(h[3][3], 0.f));

            f32x4 D[4];
            {   // t1 = relu(h) @ W1^T  (rows pre-permuted by uperm in prepack)
                const unsigned short* Wb = wpk + W1_OFF + ij * 4096;
                #pragma unroll
                for (int t = 0; t < 4; ++t) {
                    bf16x8 a0 = *(const bf16x8*)&Wb[(16 * t + r) * 64 + 8 * q];
                    bf16x8 a1 = *(const bf16x8*)&Wb[(16 * t + r) * 64 + 32 + 8 * q];
                    f32x4 d = {0.f, 0.f, 0.f, 0.f};
                    d = __builtin_amdgcn_mfma_f32_16x16x32_bf16(a0, bA.v, d, 0, 0, 0);
                    d = __builtin_amdgcn_mfma_f32_16x16x32_bf16(a1, bB.v, d, 0, 0, 0);
                    D[t] = d;
                }
            }

            // t1 = relu(D + b1), re-assembled lane-locally for W2 matvec
            B8 cA, cB;
            {
                const f32x4 c0 = *(const f32x4*)(b1 + ij * NH + pbt[0]);
                const f32x4 c1 = *(const f32x4*)(b1 + ij * NH + pbt[1]);
                const f32x4 c2 = *(const f32x4*)(b1 + ij * NH + pbt[2]);
                const f32x4 c3 = *(const f32x4*)(b1 + ij * NH + pbt[3]);
                cA.u[0] = pack2(fmaxf(D[0][0] + c0[0], 0.f), fmaxf(D[0][1] + c0[1], 0.f));
                cA.u[1] = pack2(fmaxf(D[0][2] + c0[2], 0.f), fmaxf(D[0][3] + c0[3], 0.f));
                cA.u[2] = pack2(fmaxf(D[1][0] + c1[0], 0.f), fmaxf(D[1][1] + c1[1], 0.f));
                cA.u[3] = pack2(fmaxf(D[1][2] + c1[2], 0.f), fmaxf(D[1][3] + c1[3], 0.f));
                cB.u[0] = pack2(fmaxf(D[2][0] + c2[0], 0.f), fmaxf(D[2][1] + c2[1], 0.f));
                cB.u[1] = pack2(fmaxf(D[2][2] + c2[2], 0.f), fmaxf(D[2][3] + c2[3], 0.f));
                cB.u[2] = pack2(fmaxf(D[3][0] + c3[0], 0.f), fmaxf(D[3][1] + c3[1], 0.f));
                cB.u[3] = pack2(fmaxf(D[3][2] + c3[2], 0.f), fmaxf(D[3][3] + c3[3], 0.f));
            }

            {   // t2 = t1 @ W2^T
                const unsigned short* Wb = wpk + W2_OFF + ij * 4096;
                #pragma unroll
                for (int t = 0; t < 4; ++t) {
                    bf16x8 a0 = *(const bf16x8*)&Wb[(16 * t + r) * 64 + 8 * q];
                    bf16x8 a1 = *(const bf16x8*)&Wb[(16 * t + r) * 64 + 32 + 8 * q];
                    f32x4 d = {0.f, 0.f, 0.f, 0.f};
                    d = __builtin_amdgcn_mfma_f32_16x16x32_bf16(a0, cA.v, d, 0, 0, 0);
                    d = __builtin_amdgcn_mfma_f32_16x16x32_bf16(a1, cB.v, d, 0, 0, 0);
                    D[t] = d;
                }
            }

            // h += (t2 + b2) * sigmoid(c*Wcb + bcb)
            #pragma unroll
            for (int t = 0; t < 4; ++t) {
                const int ub = ij * NH + pbt[t];
                const f32x4 b2v = *(const f32x4*)(b2 + ub);
                const f32x4 wg  = *(const f32x4*)(Wcb + ub);
                const f32x4 bg  = *(const f32x4*)(bcb + ub);
                #pragma unroll
                for (int e = 0; e < 4; ++e) {
                    float g  = fmaf(c, wg[e], bg[e]);
                    float sg = 1.0f / (1.0f + __expf(-g));
                    h[t][e] += (D[t][e] + b2v[e]) * sg;
                }
            }
        }

        // final Linear(H,2) via padded-Wf MFMA: D rows 0/1 = (o0,o1) on q==0 lanes
        {
            B8 bA, bB;
            bA.u[0] = pack2(fmaxf(h[0][0], 0.f), fmaxf(h[0][1], 0.f));
            bA.u[1] = pack2(fmaxf(h[0][2], 0.f), fmaxf(h[0][3], 0.f));
            bA.u[2] = pack2(fmaxf(h[1][0], 0.f), fmaxf(h[1][1], 0.f));
            bA.u[3] = pack2(fmaxf(h[1][2], 0.f), fmaxf(h[1][3], 0.f));
            bB.u[0] = pack2(fmaxf(h[2][0], 0.f), fmaxf(h[2][1], 0.f));
            bB.u[1] = pack2(fmaxf(h[2][2], 0.f), fmaxf(h[2][3], 0.f));
            bB.u[2] = pack2(fmaxf(h[3][0], 0.f), fmaxf(h[3][1], 0.f));
            bB.u[3] = pack2(fmaxf(h[3][2], 0.f), fmaxf(h[3][3], 0.f));

            const unsigned short* Wb = wpk + WF_OFF + i * 1024;
            bf16x8 a0 = *(const bf16x8*)&Wb[r * 64 + 8 * q];
            bf16x8 a1 = *(const bf16x8*)&Wb[r * 64 + 32 + 8 * q];
            f32x4 d = {0.f, 0.f, 0.f, 0.f};
            d = __builtin_amdgcn_mfma_f32_16x16x32_bf16(a0, bA.v, d, 0, 0, 0);
            d = __builtin_amdgcn_mfma_f32_16x16x32_bf16(a1, bB.v, d, 0, 0, 0);
            float o0 = d[0] + bf_[2 * i];
            float o1 = d[1] + bf_[2 * i + 1];
            float sp = log1pf(__expf(o0)) + 1e-3f;   // softplus + 1e-3
            z = fmaf(sp, z, o1);
            logdet += __logf(sp);
        }
    }

    if (q == 0)
        out[(size_t)n * ROWLEN + 2 * ND] = fmaf(-0.5f, z * z, logdet) - 0.91893853320467274178f;
}

extern "C" void kernel_launch(void* const* d_in, const int* in_sizes, int n_in,
                              void* d_out, int out_size, void* d_ws, size_t ws_size,
                              hipStream_t stream) {
    const float* trend    = (const float*)d_in[0];
    const float* seasonal = (const float*)d_in[1];
    const float* residual = (const float*)d_in[2];
    const float* Wt       = (const float*)d_in[3];
    const float* bt       = (const float*)d_in[4];
    const float* Ws       = (const float*)d_in[5];
    const float* bs       = (const float*)d_in[6];
    const float* b_init   = (const float*)d_in[7];
    const float* Wc0      = (const float*)d_in[8];
    const float* bc0      = (const float*)d_in[9];
    const float* W1       = (const float*)d_in[10];
    const float* b1       = (const float*)d_in[11];
    const float* W2       = (const float*)d_in[12];
    const float* b2       = (const float*)d_in[13];
    const float* Wcb      = (const float*)d_in[14];
    const float* bcb      = (const float*)d_in[15];
    const float* Wf       = (const float*)d_in[16];
    const float* bfin     = (const float*)d_in[17];
    float* out            = (float*)d_out;
    unsigned short* wpk   = (unsigned short*)d_ws;

    hipLaunchKernelGGL(prepack, dim3(WS_ELEMS / 256), dim3(256), 0, stream, W1, W2, Wf, wpk);

    const int nrows = NB * NT;                    // 65536
    hipLaunchKernelGGL(nf_main, dim3(nrows / 64), dim3(256), 0, stream,
                       trend, seasonal, residual, Wt, bt, Ws, bs,
                       b_init, Wc0, bc0, b1, b2, Wcb, bcb, bfin, wpk, out);
}

// Round 2
// 348.170 us; speedup vs baseline: 1.0177x; 1.0075x over previous
//
#include <hip/hip_runtime.h>

#define NB 32
#define NT 2048
#define ND 512
#define NH 64
#define NS 3
#define NBLKS 2
#define ROWLEN (2*ND + 1)   // 1025 floats per output row

typedef __attribute__((ext_vector_type(8))) short bf16x8;   // 8 bf16 = 4 VGPR (guide §3)
typedef float f32x4 __attribute__((ext_vector_type(4)));

// bf16 packed-weight workspace layout (ushort elements)
#define W1_OFF 0
#define W2_OFF 24576
#define WF_OFF 49152
#define WS_ELEMS 52224      // = 104448 bytes

__device__ __forceinline__ unsigned int f2bf(float f) {      // RNE f32->bf16
    unsigned int u = __float_as_uint(f);
    return (u + 0x7FFFu + ((u >> 16) & 1u)) >> 16;
}
__device__ __forceinline__ unsigned int pack2(float a, float b) {
    return f2bf(a) | (f2bf(b) << 16);
}

// Unit relabeling: packed row s holds LOGICAL unit uperm(s).
// Chosen so MFMA D-slots (16t+4q+e) of lane (r,q) are exactly the units that
// lane needs for the next matvec's B-fragment ({8q..8q+7} u {32+8q..32+8q+7}).
// => hidden-state chains entirely in registers: no LDS, no barriers.
__device__ __forceinline__ int uperm(int s) {
    return (((s >> 2) & 3) << 3) + (((s >> 4) & 1) << 2) + (s & 3) + ((s >> 5) << 5);
}

// One-shot (per launch) f32 -> bf16 weight conversion into d_ws.
// W1,W2: [S][NBLK][64][64] flat, rows gathered through uperm.
// Wf: [S][2][64] -> padded [S][16][64] (rows>=2 zero), no permutation (outputs
// land on D rows 0,1 which are slots 0,1 = logical rows 0,1).
__global__ __launch_bounds__(256) void prepack(
    const float* __restrict__ W1, const float* __restrict__ W2,
    const float* __restrict__ Wf, unsigned short* __restrict__ ws)
{
    int idx = blockIdx.x * 256 + threadIdx.x;
    if (idx < 24576) {
        int mat = idx >> 12, s = (idx >> 6) & 63, k = idx & 63;
        ws[W1_OFF + idx] = (unsigned short)f2bf(W1[(mat << 12) + uperm(s) * 64 + k]);
    } else if (idx < 49152) {
        int o = idx - 24576;
        int mat = o >> 12, s = (o >> 6) & 63, k = o & 63;
        ws[W2_OFF + o] = (unsigned short)f2bf(W2[(mat << 12) + uperm(s) * 64 + k]);
    } else if (idx < WS_ELEMS) {
        int o = idx - 49152;                 // [3][16][64]
        int s = o >> 10, row = (o >> 6) & 15, m = o & 63;
        float v = (row < 2) ? Wf[s * 128 + row * 64 + m] : 0.0f;
        ws[WF_OFF + o] = (unsigned short)f2bf(v);
    }
}

// Block = 256 threads (4 waves) handles 64 rows.
//  - feature part: 64 rows x 1024 coalesced f32 stores (the HBM floor), issued first
//  - flow part: each wave runs 16 rows through the MADE flow with bf16 MFMA,
//    hidden state register-resident throughout (unit permutation trick above).
// launch_bounds (256,3): VGPR cap ~170 (3 waves/SIMD) — removes any chance of
// scratch spill from the previous 128-VGPR cap; 3 blocks/CU still plenty for
// store-drain overlap.
__global__ __launch_bounds__(256, 3) void nf_main(
    const float* __restrict__ trend, const float* __restrict__ seasonal,
    const float* __restrict__ residual,
    const float* __restrict__ Wt, const float* __restrict__ bt,
    const float* __restrict__ Ws, const float* __restrict__ bs,
    const float* __restrict__ b_init, const float* __restrict__ Wc0,
    const float* __restrict__ bc0,
    const float* __restrict__ b1, const float* __restrict__ b2,
    const float* __restrict__ Wcb, const float* __restrict__ bcb,
    const float* __restrict__ bf_, const unsigned short* __restrict__ wpk,
    float* __restrict__ out)
{
    __shared__ float s_tr[64], s_se[64];

    const int tid  = threadIdx.x;
    const int row0 = blockIdx.x * 64;

    if (tid < 64) { s_tr[tid] = trend[row0 + tid]; s_se[tid] = seasonal[row0 + tid]; }

    // flow-part sample indices; issue the residual loads EARLY so they don't
    // queue behind 256 outstanding stores when the flow needs them.
    const int lane = tid & 63;
    const int wv_  = tid >> 6;
    const int r    = lane & 15;      // sample within wave tile; A-frag row, D col
    const int q    = lane >> 4;      // k-quad
    const int n    = row0 + wv_ * 16 + r;
    const float x  = residual[n];
    const float c  = ((n & (NT - 1)) == 0) ? 0.0f : residual[n - 1];

    __syncthreads();

    // ---------- feature part: fire-and-forget stores ----------
    {
        float wv[4], bv[4];
        #pragma unroll
        for (int j = 0; j < 4; ++j) {
            int cc = tid + 256 * j;
            if (cc < ND) { wv[j] = Wt[cc];      bv[j] = bt[cc]; }
            else         { wv[j] = Ws[cc - ND]; bv[j] = bs[cc - ND]; }
        }
        for (int rr = 0; rr < 64; ++rr) {
            float a = s_tr[rr], sv = s_se[rr];
            float* rp = out + (size_t)(row0 + rr) * ROWLEN;
            #pragma unroll
            for (int j = 0; j < 4; ++j) {
                int cc = tid + 256 * j;
                rp[cc] = fmaf((cc < ND) ? a : sv, wv[j], bv[j]);
            }
        }
    }

    // ---------- flow part (register-resident, no LDS, no barriers) ----------
    // logical-unit base for D slot (16t+4q+e): unit = pbt[t] + e
    const int pb0 = 8 * q;
    const int pbt[4] = {pb0, pb0 + 4, pb0 + 32, pb0 + 36};

    union B8 { unsigned int u[4]; bf16x8 v; };

    float z = x, logdet = 0.0f;

    for (int i = 0; i < NS; ++i) {
        float h[4][4];
        #pragma unroll
        for (int t = 0; t < 4; ++t) {
            const int ub = i * NH + pbt[t];
            const f32x4 wc  = *(const f32x4*)(Wc0 + ub);
            const f32x4 b0v = *(const f32x4*)(bc0 + ub);
            const f32x4 biv = *(const f32x4*)(b_init + ub);
            #pragma unroll
            for (int e = 0; e < 4; ++e) h[t][e] = fmaf(c, wc[e], b0v[e] + biv[e]);
        }

        #pragma unroll
        for (int j = 0; j < NBLKS; ++j) {
            const int ij = i * NBLKS + j;

            // B-fragments = relu(h), assembled lane-locally:
            // bA regs e'=0..7 <-> units 8q+e', bB <-> units 32+8q+e'
            B8 bA, bB;
            bA.u[0] = pack2(fmaxf(h[0][0], 0.f), fmaxf(h[0][1], 0.f));
            bA.u[1] = pack2(fmaxf(h[0][2], 0.f), fmaxf(h[0][3], 0.f));
            bA.u[2] = pack2(fmaxf(h[1][0], 0.f), fmaxf(h[1][1], 0.f));
            bA.u[3] = pack2(fmaxf(h[1][2], 0.f), fmaxf(h[1][3], 0.f));
            bB.u[0] = pack2(fmaxf(h[2][0], 0.f), fmaxf(h[2][1], 0.f));
            bB.u[1] = pack2(fmaxf(h[2][2], 0.f), fmaxf(h[2][3], 0.f));
            bB.u[2] = pack2(fmaxf(h[3][0], 0.f), fmaxf(h[3][1], 0.f));
            bB.u[3] = pack2(fmaxf(h[3][2], 0.f), fmaxf(h[3][3], 0.f));

            f32x4 D[4];
            {   // t1 = relu(h) @ W1^T  (rows pre-permuted by uperm in prepack)
                const unsigned short* Wb = wpk + W1_OFF + ij * 4096;
                #pragma unroll
                for (int t = 0; t < 4; ++t) {
                    bf16x8 a0 = *(const bf16x8*)&Wb[(16 * t + r) * 64 + 8 * q];
                    bf16x8 a1 = *(const bf16x8*)&Wb[(16 * t + r) * 64 + 32 + 8 * q];
                    f32x4 d = {0.f, 0.f, 0.f, 0.f};
                    d = __builtin_amdgcn_mfma_f32_16x16x32_bf16(a0, bA.v, d, 0, 0, 0);
                    d = __builtin_amdgcn_mfma_f32_16x16x32_bf16(a1, bB.v, d, 0, 0, 0);
                    D[t] = d;
                }
            }

            // t1 = relu(D + b1), re-assembled lane-locally for W2 matvec
            B8 cA, cB;
            {
                const f32x4 c0 = *(const f32x4*)(b1 + ij * NH + pbt[0]);
                const f32x4 c1 = *(const f32x4*)(b1 + ij * NH + pbt[1]);
                const f32x4 c2 = *(const f32x4*)(b1 + ij * NH + pbt[2]);
                const f32x4 c3 = *(const f32x4*)(b1 + ij * NH + pbt[3]);
                cA.u[0] = pack2(fmaxf(D[0][0] + c0[0], 0.f), fmaxf(D[0][1] + c0[1], 0.f));
                cA.u[1] = pack2(fmaxf(D[0][2] + c0[2], 0.f), fmaxf(D[0][3] + c0[3], 0.f));
                cA.u[2] = pack2(fmaxf(D[1][0] + c1[0], 0.f), fmaxf(D[1][1] + c1[1], 0.f));
                cA.u[3] = pack2(fmaxf(D[1][2] + c1[2], 0.f), fmaxf(D[1][3] + c1[3], 0.f));
                cB.u[0] = pack2(fmaxf(D[2][0] + c2[0], 0.f), fmaxf(D[2][1] + c2[1], 0.f));
                cB.u[1] = pack2(fmaxf(D[2][2] + c2[2], 0.f), fmaxf(D[2][3] + c2[3], 0.f));
                cB.u[2] = pack2(fmaxf(D[3][0] + c3[0], 0.f), fmaxf(D[3][1] + c3[1], 0.f));
                cB.u[3] = pack2(fmaxf(D[3][2] + c3[2], 0.f), fmaxf(D[3][3] + c3[3], 0.f));
            }

            {   // t2 = t1 @ W2^T
                const unsigned short* Wb = wpk + W2_OFF + ij * 4096;
                #pragma unroll
                for (int t = 0; t < 4; ++t) {
                    bf16x8 a0 = *(const bf16x8*)&Wb[(16 * t + r) * 64 + 8 * q];
                    bf16x8 a1 = *(const bf16x8*)&Wb[(16 * t + r) * 64 + 32 + 8 * q];
                    f32x4 d = {0.f, 0.f, 0.f, 0.f};
                    d = __builtin_amdgcn_mfma_f32_16x16x32_bf16(a0, cA.v, d, 0, 0, 0);
                    d = __builtin_amdgcn_mfma_f32_16x16x32_bf16(a1, cB.v, d, 0, 0, 0);
                    D[t] = d;
                }
            }

            // h += (t2 + b2) * sigmoid(c*Wcb + bcb)
            #pragma unroll
            for (int t = 0; t < 4; ++t) {
                const int ub = ij * NH + pbt[t];
                const f32x4 b2v = *(const f32x4*)(b2 + ub);
                const f32x4 wg  = *(const f32x4*)(Wcb + ub);
                const f32x4 bg  = *(const f32x4*)(bcb + ub);
                #pragma unroll
                for (int e = 0; e < 4; ++e) {
                    float g  = fmaf(c, wg[e], bg[e]);
                    float sg = 1.0f / (1.0f + __expf(-g));
                    h[t][e] += (D[t][e] + b2v[e]) * sg;
                }
            }
        }

        // final Linear(H,2) via padded-Wf MFMA: D rows 0/1 = (o0,o1) on q==0 lanes
        {
            B8 bA, bB;
            bA.u[0] = pack2(fmaxf(h[0][0], 0.f), fmaxf(h[0][1], 0.f));
            bA.u[1] = pack2(fmaxf(h[0][2], 0.f), fmaxf(h[0][3], 0.f));
            bA.u[2] = pack2(fmaxf(h[1][0], 0.f), fmaxf(h[1][1], 0.f));
            bA.u[3] = pack2(fmaxf(h[1][2], 0.f), fmaxf(h[1][3], 0.f));
            bB.u[0] = pack2(fmaxf(h[2][0], 0.f), fmaxf(h[2][1], 0.f));
            bB.u[1] = pack2(fmaxf(h[2][2], 0.f), fmaxf(h[2][3], 0.f));
            bB.u[2] = pack2(fmaxf(h[3][0], 0.f), fmaxf(h[3][1], 0.f));
            bB.u[3] = pack2(fmaxf(h[3][2], 0.f), fmaxf(h[3][3], 0.f));

            const unsigned short* Wb = wpk + WF_OFF + i * 1024;
            bf16x8 a0 = *(const bf16x8*)&Wb[r * 64 + 8 * q];
            bf16x8 a1 = *(const bf16x8*)&Wb[r * 64 + 32 + 8 * q];
            f32x4 d = {0.f, 0.f, 0.f, 0.f};
            d = __builtin_amdgcn_mfma_f32_16x16x32_bf16(a0, bA.v, d, 0, 0, 0);
            d = __builtin_amdgcn_mfma_f32_16x16x32_bf16(a1, bB.v, d, 0, 0, 0);
            float o0 = d[0] + bf_[2 * i];
            float o1 = d[1] + bf_[2 * i + 1];
            float sp = log1pf(__expf(o0)) + 1e-3f;   // softplus + 1e-3
            z = fmaf(sp, z, o1);
            logdet += __logf(sp);
        }
    }

    if (q == 0)
        out[(size_t)n * ROWLEN + 2 * ND] = fmaf(-0.5f, z * z, logdet) - 0.91893853320467274178f;
}

extern "C" void kernel_launch(void* const* d_in, const int* in_sizes, int n_in,
                              void* d_out, int out_size, void* d_ws, size_t ws_size,
                              hipStream_t stream) {
    const float* trend    = (const float*)d_in[0];
    const float* seasonal = (const float*)d_in[1];
    const float* residual = (const float*)d_in[2];
    const float* Wt       = (const float*)d_in[3];
    const float* bt       = (const float*)d_in[4];
    const float* Ws       = (const float*)d_in[5];
    const float* bs       = (const float*)d_in[6];
    const float* b_init   = (const float*)d_in[7];
    const float* Wc0      = (const float*)d_in[8];
    const float* bc0      = (const float*)d_in[9];
    const float* W1       = (const float*)d_in[10];
    const float* b1       = (const float*)d_in[11];
    const float* W2       = (const float*)d_in[12];
    const float* b2       = (const float*)d_in[13];
    const float* Wcb      = (const float*)d_in[14];
    const float* bcb      = (const float*)d_in[15];
    const float* Wf       = (const float*)d_in[16];
    const float* bfin     = (const float*)d_in[17];
    float* out            = (float*)d_out;
    unsigned short* wpk   = (unsigned short*)d_ws;

    hipLaunchKernelGGL(prepack, dim3(WS_ELEMS / 256), dim3(256), 0, stream, W1, W2, Wf, wpk);

    const int nrows = NB * NT;                    // 65536
    hipLaunchKernelGGL(nf_main, dim3(nrows / 64), dim3(256), 0, stream,
                       trend, seasonal, residual, Wt, bt, Ws, bs,
                       b_init, Wc0, bc0, b1, b2, Wcb, bcb, bfin, wpk, out);
}